// Round 5
// baseline (861.390 us; speedup 1.0000x reference)
//
#include <hip/hip_runtime.h>

#define B_   64
#define T_   1024
#define D_   128
#define SCALE_ 0.08838834764831845f
#define FILL_  (-4294967295.0f)
#define VST  132   // Vlds row stride (f32): 528 B = 16B-aligned; cols swizzled

typedef __attribute__((ext_vector_type(8))) short short8v;
typedef __attribute__((ext_vector_type(4))) float f32x4;

#define MFMA16(A,Bv,C) __builtin_amdgcn_mfma_f32_16x16x32_bf16((A),(Bv),(C),0,0,0)

// truncation-split: f ~= hi + lo with hi,lo bf16 (error ~2^-17 rel)
__device__ __forceinline__ void split8(const float f[8], short8v& h, short8v& l) {
#pragma unroll
    for (int i = 0; i < 8; ++i) {
        const unsigned int u = __float_as_uint(f[i]);
        h[i] = (short)(u >> 16);
        const float r = f[i] - __uint_as_float(u & 0xffff0000u);
        l[i] = (short)(__float_as_uint(r) >> 16);
    }
}
__device__ __forceinline__ unsigned int packsplit(float f) {
    const unsigned int u = __float_as_uint(f);
    const unsigned int hi = u >> 16;
    const float r = f - __uint_as_float(u & 0xffff0000u);
    const unsigned int lo = __float_as_uint(r) >> 16;
    return hi | (lo << 16);
}

// One block per (batch, 32-row q-tile); 512 threads = 8 waves.
// QK^T (validated r3): wave w owns k-cols [w*128, w*128+128); hi/lo split x3 MFMA.
// PV (d-split): wave w owns d-cols [w*16, w*16+16). 16 chunks of 64 k:
//   owner wave (kc>>1) publishes P chunk -> Pc[64][33] u32 (hi|lo);
//   all waves stage V chunk coalesced -> Vlds[64][VST] f32, d-swizzled (bits4-5 ^= row bits3-4);
//   each wave: A-frags from Pc (~2-way, free), B-frags from Vlds (2-way, free), 12 MFMA.
// Direct register->global result store (no cross-wave O reduction).
// Grid swizzled XCD-aware: 8 q-tiles of one batch per XCD (K/V L2 reuse).
__global__ __launch_bounds__(512, 4)
void mha_kernel(const float* __restrict__ Kp, const float* __restrict__ Vp,
                const float* __restrict__ Qp, const unsigned char* __restrict__ Mp,
                const float* __restrict__ QMp, float* __restrict__ Orp,
                float* __restrict__ Oap)
{
    __shared__ __align__(16) float Vlds[64 * VST];   // 33792 B
    __shared__ unsigned int Pc[64 * 33];             // 8448 B
    __shared__ float redA[8 * 32];
    __shared__ float redB[8 * 32];

    const int tid  = threadIdx.x;
    const int w    = tid >> 6;
    const int lane = tid & 63;
    const int g    = lane >> 4;
    const int c    = lane & 15;
    // XCD-aware bijective swizzle: grid=2048=8*256, chunked per XCD
    const int wg   = (blockIdx.x & 7) * 256 + (blockIdx.x >> 3);
    const int b    = wg >> 5;
    const int q0   = (wg & 31) << 5;

    // ---- mask dtype auto-detect (u8 bool vs i32) ----
    const unsigned int* mw = (const unsigned int*)Mp;
    unsigned int bad = 0u;
#pragma unroll
    for (int i = 0; i < 16; ++i) bad |= (unsigned int)(mw[i] > 1u);
    const bool m32 = (bad == 0u);

    const size_t bt = (size_t)b * T_;

    // =================== QK^T ===================
    f32x4 acc[2][8];
#pragma unroll
    for (int mt = 0; mt < 2; ++mt)
#pragma unroll
        for (int nt = 0; nt < 8; ++nt) acc[mt][nt] = (f32x4)0.f;

#pragma unroll
    for (int ks = 0; ks < 4; ++ks) {
        short8v qh[2], ql[2];
#pragma unroll
        for (int mt = 0; mt < 2; ++mt) {
            const float* qp = Qp + (bt + q0 + mt*16 + c) * D_ + ks*32 + g*8;
            float f[8];
#pragma unroll
            for (int i = 0; i < 8; ++i) f[i] = qp[i];
            split8(f, qh[mt], ql[mt]);
        }
#pragma unroll
        for (int nt = 0; nt < 8; ++nt) {
            const float* kp = Kp + (bt + w*128 + nt*16 + c) * D_ + ks*32 + g*8;
            float f[8];
#pragma unroll
            for (int i = 0; i < 8; ++i) f[i] = kp[i];
            short8v kh, kl;
            split8(f, kh, kl);
#pragma unroll
            for (int mt = 0; mt < 2; ++mt) {
                acc[mt][nt] = MFMA16(qh[mt], kh, acc[mt][nt]);
                acc[mt][nt] = MFMA16(qh[mt], kl, acc[mt][nt]);
                acc[mt][nt] = MFMA16(ql[mt], kh, acc[mt][nt]);
            }
        }
    }

    // =================== mask + scale + softmax ===================
    float rmax[2][4];
#pragma unroll
    for (int mt = 0; mt < 2; ++mt)
#pragma unroll
    for (int rg = 0; rg < 4; ++rg) {
        const int row = mt*16 + g*4 + rg;
        const size_t mrow = (bt + q0 + row) * (size_t)T_ + w*128;
        float rm = -3.0e38f;
        if (m32) {
            const int* mi = (const int*)Mp;
#pragma unroll
            for (int nt = 0; nt < 8; ++nt) {
                float s = acc[mt][nt][rg] * SCALE_;
                if (mi[mrow + nt*16 + c]) s = FILL_;
                acc[mt][nt][rg] = s;
                rm = fmaxf(rm, s);
            }
        } else {
#pragma unroll
            for (int nt = 0; nt < 8; ++nt) {
                float s = acc[mt][nt][rg] * SCALE_;
                if (Mp[mrow + nt*16 + c]) s = FILL_;
                acc[mt][nt][rg] = s;
                rm = fmaxf(rm, s);
            }
        }
        rmax[mt][rg] = rm;
    }
#pragma unroll
    for (int mt = 0; mt < 2; ++mt)
#pragma unroll
    for (int rg = 0; rg < 4; ++rg)
#pragma unroll
        for (int off = 1; off < 16; off <<= 1)
            rmax[mt][rg] = fmaxf(rmax[mt][rg], __shfl_xor(rmax[mt][rg], off, 64));
    if (c == 0) {
#pragma unroll
        for (int mt = 0; mt < 2; ++mt)
#pragma unroll
        for (int rg = 0; rg < 4; ++rg)
            redA[w*32 + mt*16 + g*4 + rg] = rmax[mt][rg];
    }
    __syncthreads();
    float rsum[2][4];
#pragma unroll
    for (int mt = 0; mt < 2; ++mt)
#pragma unroll
    for (int rg = 0; rg < 4; ++rg) {
        const int row = mt*16 + g*4 + rg;
        float m = redA[row];
#pragma unroll
        for (int w2 = 1; w2 < 8; ++w2) m = fmaxf(m, redA[w2*32 + row]);
        float s = 0.f;
#pragma unroll
        for (int nt = 0; nt < 8; ++nt) {
            const float e = __expf(acc[mt][nt][rg] - m);
            acc[mt][nt][rg] = e;
            s += e;
        }
#pragma unroll
        for (int off = 1; off < 16; off <<= 1) s += __shfl_xor(s, off, 64);
        rsum[mt][rg] = s;
    }
    if (c == 0) {
#pragma unroll
        for (int mt = 0; mt < 2; ++mt)
#pragma unroll
        for (int rg = 0; rg < 4; ++rg)
            redB[w*32 + mt*16 + g*4 + rg] = rsum[mt][rg];
    }
    __syncthreads();

    // finalize p = e * query_mask / sum; store attn; pack hi/lo for PV
    unsigned int pk[2][8][4];
#pragma unroll
    for (int mt = 0; mt < 2; ++mt)
#pragma unroll
    for (int rg = 0; rg < 4; ++rg) {
        const int row = mt*16 + g*4 + rg;
        float ssum = redB[row];
#pragma unroll
        for (int w2 = 1; w2 < 8; ++w2) ssum += redB[w2*32 + row];
        const float inv = QMp[bt + q0 + row] / ssum;
        const size_t arow = (bt + q0 + row) * (size_t)T_ + w*128;
#pragma unroll
        for (int nt = 0; nt < 8; ++nt) {
            const float p = acc[mt][nt][rg] * inv;
            Oap[arow + nt*16 + c] = p;
            pk[mt][nt][rg] = packsplit(p);
        }
    }

    // =================== PV (d-split) ===================
    f32x4 o[2];
    o[0] = (f32x4)0.f;
    o[1] = (f32x4)0.f;

    const int vrow = tid >> 3;    // 0..63: V stage row
    const int vcg  = tid & 7;     // col group (16 f32)

    // static-index P publish (rule #20: no runtime pk indices)
#define WRITE_P(NB)                                                        \
    {                                                                      \
        _Pragma("unroll")                                                  \
        for (int mt = 0; mt < 2; ++mt)                                     \
        _Pragma("unroll")                                                  \
        for (int n4 = 0; n4 < 4; ++n4)                                     \
        _Pragma("unroll")                                                  \
        for (int rg = 0; rg < 4; ++rg)                                     \
            Pc[(n4*16 + c)*33 + mt*16 + g*4 + rg] = pk[mt][(NB) + n4][rg]; \
    }

    for (int kc = 0; kc < 16; ++kc) {
        __syncthreads();   // WAR vs previous chunk's reads
        if (w == (kc >> 1)) {
            if (kc & 1) { WRITE_P(4) } else { WRITE_P(0) }
        }
        // cooperative coalesced V stage, d-swizzled (bits4-5 ^= k bits3-4)
        {
            const float* vp = Vp + (bt + kc*64 + vrow) * D_ + vcg*16;
            float* dst = &Vlds[vrow * VST + ((vcg ^ ((vrow >> 3) & 3)) << 4)];
#pragma unroll
            for (int j = 0; j < 4; ++j)
                *(float4*)&dst[j*4] = *(const float4*)&vp[j*4];
        }
        __syncthreads();
#pragma unroll
        for (int ks2 = 0; ks2 < 2; ++ks2) {
            // A fragments (P): row q = mt*16 + c, k = ks2*32 + g*8 + i
            short8v ph[2], pl[2];
#pragma unroll
            for (int mt = 0; mt < 2; ++mt) {
                const int base = (ks2*32 + g*8)*33 + mt*16 + c;
#pragma unroll
                for (int i = 0; i < 8; ++i) {
                    const unsigned int x = Pc[base + i*33];
                    ph[mt][i] = (short)(x & 0xffffu);
                    pl[mt][i] = (short)(x >> 16);
                }
            }
            // B fragment (V): col d = w*16 + c, k = ks2*32 + g*8 + i
            float fv[8];
            {
                const int kb   = ks2*32 + g*8;
                const int dsw  = (w*16 + c) ^ ((((kb) >> 3) & 3) << 4);  // (kb>>3)&3 == g, const over i
                const int base = kb * VST + dsw;
#pragma unroll
                for (int i = 0; i < 8; ++i) fv[i] = Vlds[base + i * VST];
            }
            short8v vh, vl;
            split8(fv, vh, vl);
#pragma unroll
            for (int mt = 0; mt < 2; ++mt) {
                o[mt] = MFMA16(ph[mt], vh, o[mt]);
                o[mt] = MFMA16(ph[mt], vl, o[mt]);
                o[mt] = MFMA16(pl[mt], vh, o[mt]);
            }
        }
    }

    // =================== result write (direct, no reduction) ===================
#pragma unroll
    for (int mt = 0; mt < 2; ++mt)
#pragma unroll
    for (int rg = 0; rg < 4; ++rg)
        Orp[(bt + q0 + mt*16 + g*4 + rg) * D_ + w*16 + c] = o[mt][rg];
}

extern "C" void kernel_launch(void* const* d_in, const int* in_sizes, int n_in,
                              void* d_out, int out_size, void* d_ws, size_t ws_size,
                              hipStream_t stream)
{
    const float* Kp  = (const float*)d_in[0];                 // key   [B,T,D]
    const float* Vp  = (const float*)d_in[1];                 // value [B,T,D]
    const float* Qp  = (const float*)d_in[2];                 // query [B,T,D]
    const unsigned char* Mp = (const unsigned char*)d_in[3];  // mask  [B,T,T] (i32, auto-detected)
    const float* QMp = (const float*)d_in[4];                 // query_mask [B,T,1]
    float* Orp = (float*)d_out;                               // result [B,T,D] first
    float* Oap = Orp + (size_t)B_ * T_ * D_;                  // then attn [B,T,T]

    hipLaunchKernelGGL(mha_kernel, dim3(B_ * 32), dim3(512), 0, stream,
                       Kp, Vp, Qp, Mp, QMp, Orp, Oap);
}

// Round 6
// 829.269 us; speedup vs baseline: 1.0387x; 1.0387x over previous
//
#include <hip/hip_runtime.h>

#define B_   64
#define T_   1024
#define D_   128
#define SCALE_ 0.08838834764831845f
#define FILL_  (-4294967295.0f)

typedef __attribute__((ext_vector_type(8))) short short8v;
typedef __attribute__((ext_vector_type(4))) float f32x4;

#define MFMA16(A,Bv,C) __builtin_amdgcn_mfma_f32_16x16x32_bf16((A),(Bv),(C),0,0,0)

// truncation-split: f ~= hi + lo with hi,lo bf16 (error ~2^-17 rel)
__device__ __forceinline__ void split8(const float f[8], short8v& h, short8v& l) {
#pragma unroll
    for (int i = 0; i < 8; ++i) {
        const unsigned int u = __float_as_uint(f[i]);
        h[i] = (short)(u >> 16);
        const float r = f[i] - __uint_as_float(u & 0xffff0000u);
        l[i] = (short)(__float_as_uint(r) >> 16);
    }
}
__device__ __forceinline__ unsigned int packsplit(float f) {
    const unsigned int u = __float_as_uint(f);
    const unsigned int hi = u >> 16;
    const float r = f - __uint_as_float(u & 0xffff0000u);
    const unsigned int lo = __float_as_uint(r) >> 16;
    return hi | (lo << 16);
}

// One block per (batch, 32-row q-tile); 512 threads = 8 waves.
// QK^T (validated r3/r5): wave w owns k-cols [w*128, w*128+128); hi/lo split x3 MFMA.
// PV (d-split, no V staging): wave w owns d-cols [w*16, w*16+16).
//   8 chunks of 128 k: owner wave kc publishes its whole P slice -> Pc[128][33] u32
//   (reads 2-way bank-free, stride 33); V B-frags read DIRECT from global
//   (4x64B segments per instr, L2-resident per XCD). LDS ~19KB, VGPR ~64
//   -> ~4 blocks/CU to hide global-V latency.
// attn/result stores nontemporal (write-once streams, bypass L2).
// Grid swizzled XCD-aware: 8 batches per XCD (K/V/mask L2 reuse).
__global__ __launch_bounds__(512, 4)
void mha_kernel(const float* __restrict__ Kp, const float* __restrict__ Vp,
                const float* __restrict__ Qp, const unsigned char* __restrict__ Mp,
                const float* __restrict__ QMp, float* __restrict__ Orp,
                float* __restrict__ Oap)
{
    __shared__ unsigned int Pc[128 * 33];   // 16896 B
    __shared__ float redA[8 * 32];
    __shared__ float redB[8 * 32];

    const int tid  = threadIdx.x;
    const int w    = tid >> 6;
    const int lane = tid & 63;
    const int g    = lane >> 4;
    const int c    = lane & 15;
    // XCD-aware bijective swizzle: grid=2048=8*256, chunked per XCD
    const int wg   = (blockIdx.x & 7) * 256 + (blockIdx.x >> 3);
    const int b    = wg >> 5;
    const int q0   = (wg & 31) << 5;

    // ---- mask dtype auto-detect (u8 bool vs i32) ----
    const unsigned int* mw = (const unsigned int*)Mp;
    unsigned int bad = 0u;
#pragma unroll
    for (int i = 0; i < 16; ++i) bad |= (unsigned int)(mw[i] > 1u);
    const bool m32 = (bad == 0u);

    const size_t bt = (size_t)b * T_;

    // =================== QK^T ===================
    f32x4 acc[2][8];
#pragma unroll
    for (int mt = 0; mt < 2; ++mt)
#pragma unroll
        for (int nt = 0; nt < 8; ++nt) acc[mt][nt] = (f32x4)0.f;

#pragma unroll
    for (int ks = 0; ks < 4; ++ks) {
        short8v qh[2], ql[2];
#pragma unroll
        for (int mt = 0; mt < 2; ++mt) {
            const float* qp = Qp + (bt + q0 + mt*16 + c) * D_ + ks*32 + g*8;
            float f[8];
#pragma unroll
            for (int i = 0; i < 8; ++i) f[i] = qp[i];
            split8(f, qh[mt], ql[mt]);
        }
#pragma unroll
        for (int nt = 0; nt < 8; ++nt) {
            const float* kp = Kp + (bt + w*128 + nt*16 + c) * D_ + ks*32 + g*8;
            float f[8];
#pragma unroll
            for (int i = 0; i < 8; ++i) f[i] = kp[i];
            short8v kh, kl;
            split8(f, kh, kl);
#pragma unroll
            for (int mt = 0; mt < 2; ++mt) {
                acc[mt][nt] = MFMA16(qh[mt], kh, acc[mt][nt]);
                acc[mt][nt] = MFMA16(qh[mt], kl, acc[mt][nt]);
                acc[mt][nt] = MFMA16(ql[mt], kh, acc[mt][nt]);
            }
        }
    }

    // =================== mask + scale + softmax ===================
    float rmax[2][4];
#pragma unroll
    for (int mt = 0; mt < 2; ++mt)
#pragma unroll
    for (int rg = 0; rg < 4; ++rg) {
        const int row = mt*16 + g*4 + rg;
        const size_t mrow = (bt + q0 + row) * (size_t)T_ + w*128;
        float rm = -3.0e38f;
        if (m32) {
            const int* mi = (const int*)Mp;
#pragma unroll
            for (int nt = 0; nt < 8; ++nt) {
                float s = acc[mt][nt][rg] * SCALE_;
                if (mi[mrow + nt*16 + c]) s = FILL_;
                acc[mt][nt][rg] = s;
                rm = fmaxf(rm, s);
            }
        } else {
#pragma unroll
            for (int nt = 0; nt < 8; ++nt) {
                float s = acc[mt][nt][rg] * SCALE_;
                if (Mp[mrow + nt*16 + c]) s = FILL_;
                acc[mt][nt][rg] = s;
                rm = fmaxf(rm, s);
            }
        }
        rmax[mt][rg] = rm;
    }
#pragma unroll
    for (int mt = 0; mt < 2; ++mt)
#pragma unroll
    for (int rg = 0; rg < 4; ++rg)
#pragma unroll
        for (int off = 1; off < 16; off <<= 1)
            rmax[mt][rg] = fmaxf(rmax[mt][rg], __shfl_xor(rmax[mt][rg], off, 64));
    if (c == 0) {
#pragma unroll
        for (int mt = 0; mt < 2; ++mt)
#pragma unroll
        for (int rg = 0; rg < 4; ++rg)
            redA[w*32 + mt*16 + g*4 + rg] = rmax[mt][rg];
    }
    __syncthreads();
    float rsum[2][4];
#pragma unroll
    for (int mt = 0; mt < 2; ++mt)
#pragma unroll
    for (int rg = 0; rg < 4; ++rg) {
        const int row = mt*16 + g*4 + rg;
        float m = redA[row];
#pragma unroll
        for (int w2 = 1; w2 < 8; ++w2) m = fmaxf(m, redA[w2*32 + row]);
        float s = 0.f;
#pragma unroll
        for (int nt = 0; nt < 8; ++nt) {
            const float e = __expf(acc[mt][nt][rg] - m);
            acc[mt][nt][rg] = e;
            s += e;
        }
#pragma unroll
        for (int off = 1; off < 16; off <<= 1) s += __shfl_xor(s, off, 64);
        rsum[mt][rg] = s;
    }
    if (c == 0) {
#pragma unroll
        for (int mt = 0; mt < 2; ++mt)
#pragma unroll
        for (int rg = 0; rg < 4; ++rg)
            redB[w*32 + mt*16 + g*4 + rg] = rsum[mt][rg];
    }
    __syncthreads();

    // finalize p = e * query_mask / sum; store attn (nontemporal); pack hi/lo
    unsigned int pk[2][8][4];
#pragma unroll
    for (int mt = 0; mt < 2; ++mt)
#pragma unroll
    for (int rg = 0; rg < 4; ++rg) {
        const int row = mt*16 + g*4 + rg;
        float ssum = redB[row];
#pragma unroll
        for (int w2 = 1; w2 < 8; ++w2) ssum += redB[w2*32 + row];
        const float inv = QMp[bt + q0 + row] / ssum;
        const size_t arow = (bt + q0 + row) * (size_t)T_ + w*128;
#pragma unroll
        for (int nt = 0; nt < 8; ++nt) {
            const float p = acc[mt][nt][rg] * inv;
            __builtin_nontemporal_store(p, &Oap[arow + nt*16 + c]);
            pk[mt][nt][rg] = packsplit(p);
        }
    }

    // =================== PV (d-split, V direct from global) ===================
    f32x4 o[2];
    o[0] = (f32x4)0.f;
    o[1] = (f32x4)0.f;

    for (int kc = 0; kc < 8; ++kc) {
        __syncthreads();   // WAR vs previous chunk's Pc reads
        if (w == kc) {
            // publish this wave's entire P slice (static indices)
#pragma unroll
            for (int mt = 0; mt < 2; ++mt)
#pragma unroll
            for (int nt = 0; nt < 8; ++nt)
#pragma unroll
            for (int rg = 0; rg < 4; ++rg)
                Pc[(nt*16 + c)*33 + mt*16 + g*4 + rg] = pk[mt][nt][rg];
        }
        __syncthreads();
#pragma unroll
        for (int ks2 = 0; ks2 < 4; ++ks2) {
            // A fragments (P): row q = mt*16 + c, k-slot = g*8 + i
            short8v ph[2], pl[2];
#pragma unroll
            for (int mt = 0; mt < 2; ++mt) {
                const int base = (ks2*32 + g*8)*33 + mt*16 + c;
#pragma unroll
                for (int i = 0; i < 8; ++i) {
                    const unsigned int x = Pc[base + i*33];
                    ph[mt][i] = (short)(x & 0xffffu);
                    pl[mt][i] = (short)(x >> 16);
                }
            }
            // B fragment (V) direct from global: col d = w*16 + c, k = kc*128 + ks2*32 + g*8 + i
            float fv[8];
            {
                const float* vp = Vp + (bt + kc*128 + ks2*32 + g*8) * D_ + w*16 + c;
#pragma unroll
                for (int i = 0; i < 8; ++i) fv[i] = vp[(size_t)i * D_];
            }
            short8v vh, vl;
            split8(fv, vh, vl);
#pragma unroll
            for (int mt = 0; mt < 2; ++mt) {
                o[mt] = MFMA16(ph[mt], vh, o[mt]);
                o[mt] = MFMA16(ph[mt], vl, o[mt]);
                o[mt] = MFMA16(pl[mt], vh, o[mt]);
            }
        }
    }

    // =================== result write (direct, nontemporal) ===================
#pragma unroll
    for (int mt = 0; mt < 2; ++mt)
#pragma unroll
    for (int rg = 0; rg < 4; ++rg)
        __builtin_nontemporal_store(o[mt][rg],
            &Orp[(bt + q0 + mt*16 + g*4 + rg) * D_ + w*16 + c]);
}

extern "C" void kernel_launch(void* const* d_in, const int* in_sizes, int n_in,
                              void* d_out, int out_size, void* d_ws, size_t ws_size,
                              hipStream_t stream)
{
    const float* Kp  = (const float*)d_in[0];                 // key   [B,T,D]
    const float* Vp  = (const float*)d_in[1];                 // value [B,T,D]
    const float* Qp  = (const float*)d_in[2];                 // query [B,T,D]
    const unsigned char* Mp = (const unsigned char*)d_in[3];  // mask  [B,T,T] (i32, auto-detected)
    const float* QMp = (const float*)d_in[4];                 // query_mask [B,T,1]
    float* Orp = (float*)d_out;                               // result [B,T,D] first
    float* Oap = Orp + (size_t)B_ * T_ * D_;                  // then attn [B,T,T]

    hipLaunchKernelGGL(mha_kernel, dim3(B_ * 32), dim3(512), 0, stream,
                       Kp, Vp, Qp, Mp, QMp, Orp, Oap);
}